// Round 8
// baseline (22.242 us; speedup 1.0000x reference)
//
#include <hip/hip_runtime.h>

constexpr int N = 512;
constexpr int D = 128;
constexpr float MARGIN = 1.0f;
constexpr float EPS_T = 1e-16f;

// Single fused dispatch. One block per anchor i, 512 threads.
//  P1: coalesced distance row — 8 lanes per row, float4 chunks {sub, sub+8,
//      sub+16, sub+24}; 8-lane shfl_xor tree; 8 passes cover 512 rows.
//  P2: wave 0 ballot-compacts positive distances (deterministic order).
//  P3: thread's k (= tid) if negative: hinge over ~16 positives.
//  P4: fixed-tree f64 reduction -> per-block triple, written with
//      AGENT-scope atomic stores (coherence point, not per-XCD L2).
//  P5: last-arriving block (AGENT-scope ACQ_REL ticket) re-reads all 512
//      triples with AGENT-scope atomic loads (no stale L1/L2) and reduces
//      them in the same fixed tree as the old final kernel -> bitwise-same.
//      Ticket self-resets: exactly N increments per call, (old&(N-1))==N-1
//      fires exactly once from ANY starting value; finalizer stores 0.
__global__ __launch_bounds__(512, 2) void triplet_fused_k(
    const float* __restrict__ emb, const int* __restrict__ labels,
    double* __restrict__ partial, unsigned int* __restrict__ ticket,
    float* __restrict__ out)
{
    __shared__ float  ei[D];
    __shared__ float  drow[N];
    __shared__ float  posd[N];
    __shared__ int    npos_s;
    __shared__ int    last_s;
    __shared__ double red[24];   // [0..7]=sum, [8..15]=npos, [16..23]=ntrip

    const int i    = blockIdx.x;
    const int tid  = threadIdx.x;
    const int lane = tid & 63;
    const int wid  = tid >> 6;

    if (tid < D) ei[tid] = emb[(size_t)i * D + tid];
    const int lk = labels[tid];          // this thread's k-label
    const int li = labels[i];            // uniform broadcast
    __syncthreads();

    // ---- P1: coalesced distance rows ----
    const float4* ea  = reinterpret_cast<const float4*>(ei);
    const int     sub = tid & 7;         // 8 lanes per row
    #pragma unroll
    for (int p = 0; p < 8; ++p) {
        const int r = p * 64 + (tid >> 3);
        const float4* er = reinterpret_cast<const float4*>(emb + (size_t)r * D);
        float sq = 0.f;
        #pragma unroll
        for (int c = 0; c < 4; ++c) {
            const int idx = sub + 8 * c;
            float4 v = er[idx];
            float4 a = ea[idx];
            float d0 = a.x - v.x, d1 = a.y - v.y;
            float d2 = a.z - v.z, d3 = a.w - v.w;
            sq += d0 * d0 + d1 * d1 + d2 * d2 + d3 * d3;
        }
        sq += __shfl_xor(sq, 1);
        sq += __shfl_xor(sq, 2);
        sq += __shfl_xor(sq, 4);
        if (sub == 0) drow[r] = (sq > 0.f) ? sqrtf(sq) : 0.f;  // safe sqrt
    }
    __syncthreads();

    // ---- P2: deterministic positive-distance compaction (wave 0) ----
    if (wid == 0) {
        int base = 0;
        #pragma unroll
        for (int r = 0; r < 8; ++r) {
            const int j = r * 64 + lane;
            const bool pred = (labels[j] == li) && (j != i);
            const unsigned long long m = __ballot(pred);
            if (pred) posd[base + __popcll(m & ((1ull << lane) - 1ull))] = drow[j];
            base += __popcll(m);
        }
        if (lane == 0) npos_s = base;
    }
    __syncthreads();

    // ---- P3: hinge accumulation (this thread's k a negative?) ----
    const int   npos = npos_s;
    const float dik  = drow[tid];
    double sum = 0.0;
    int np_i = 0, nt_i = 0;
    if (lk != li) {
        #pragma unroll 4
        for (int p = 0; p < npos; ++p) {
            const float t = (posd[p] - dik) + MARGIN;  // reference op order
            if (t > EPS_T) { sum += (double)t; ++np_i; }
        }
        nt_i = npos;
    }

    // ---- P4: fixed-tree reduction; coherent partial publish ----
    double s = sum, p = (double)np_i, t = (double)nt_i;
    #pragma unroll
    for (int off = 32; off > 0; off >>= 1) {
        s += __shfl_down(s, off);
        p += __shfl_down(p, off);
        t += __shfl_down(t, off);
    }
    if (lane == 0) { red[wid] = s; red[8 + wid] = p; red[16 + wid] = t; }
    __syncthreads();
    if (tid == 0) {
        double S = 0.0, P = 0.0, T = 0.0;
        #pragma unroll
        for (int w = 0; w < 8; ++w) { S += red[w]; P += red[8 + w]; T += red[16 + w]; }
        __hip_atomic_store(&partial[i],         S, __ATOMIC_RELAXED, __HIP_MEMORY_SCOPE_AGENT);
        __hip_atomic_store(&partial[N + i],     P, __ATOMIC_RELAXED, __HIP_MEMORY_SCOPE_AGENT);
        __hip_atomic_store(&partial[2 * N + i], T, __ATOMIC_RELAXED, __HIP_MEMORY_SCOPE_AGENT);
        const unsigned v = __hip_atomic_fetch_add(ticket, 1u, __ATOMIC_ACQ_REL,
                                                  __HIP_MEMORY_SCOPE_AGENT);
        last_s = ((v & (unsigned)(N - 1)) == (unsigned)(N - 1)) ? 1 : 0;
    }
    __syncthreads();                      // also orders red[] reuse below

    // ---- P5: last block finalizes (same tree as the old final kernel) ----
    if (last_s) {
        double a = __hip_atomic_load(&partial[tid],         __ATOMIC_RELAXED, __HIP_MEMORY_SCOPE_AGENT);
        double b = __hip_atomic_load(&partial[N + tid],     __ATOMIC_RELAXED, __HIP_MEMORY_SCOPE_AGENT);
        double c = __hip_atomic_load(&partial[2 * N + tid], __ATOMIC_RELAXED, __HIP_MEMORY_SCOPE_AGENT);
        #pragma unroll
        for (int off = 32; off > 0; off >>= 1) {
            a += __shfl_down(a, off);
            b += __shfl_down(b, off);
            c += __shfl_down(c, off);
        }
        if (lane == 0) { red[wid] = a; red[8 + wid] = b; red[16 + wid] = c; }
        __syncthreads();
        if (tid == 0) {
            double S = 0.0, P = 0.0, T = 0.0;
            #pragma unroll
            for (int w = 0; w < 8; ++w) { S += red[w]; P += red[8 + w]; T += red[16 + w]; }
            out[0] = (float)(S / (P + 1e-16));  // loss
            out[1] = (float)(P / (T + 1e-16));  // fraction_positive
            __hip_atomic_store(ticket, 0u, __ATOMIC_RELAXED, __HIP_MEMORY_SCOPE_AGENT);
        }
    }
}

extern "C" void kernel_launch(void* const* d_in, const int* in_sizes, int n_in,
                              void* d_out, int out_size, void* d_ws, size_t ws_size,
                              hipStream_t stream) {
    const float* emb   = (const float*)d_in[0];   // [512,128] f32
    const int*   lab   = (const int*)d_in[1];     // [512] i32
    float*       out   = (float*)d_out;           // [2] f32: loss, fraction_positive

    double*       parts  = (double*)d_ws;                         // 3*N*8 = 12288 B
    unsigned int* ticket = (unsigned int*)((char*)d_ws + 3 * N * sizeof(double));

    triplet_fused_k<<<N, 512, 0, stream>>>(emb, lab, parts, ticket, out);
}

// Round 9
// 15.360 us; speedup vs baseline: 1.4481x; 1.4481x over previous
//
#include <hip/hip_runtime.h>

constexpr int N = 512;
constexpr int D = 128;
constexpr int A = 2;             // anchors per block
constexpr int NBLK = N / A;      // 256 blocks = 1 per CU, full machine
constexpr float MARGIN = 1.0f;
constexpr float EPS_T = 1e-16f;

// Two deterministic kernels. Main: 2 anchors/block, 256 blocks, 512 threads.
//  - Each block streams emb ONCE (256 KB) for two distance rows: total L2
//    traffic 64 MB (vs 128 MB at 1 anchor/block), one block-round per CU.
//  - Anchor chunks live in REGISTERS (8 float4); P1 has no LDS reads.
//  - P1: 8 lanes per row, coalesced float4 chunks, 2 shfl_xor trees/pass.
//  - P2: ALL 8 waves compact in parallel (count -> LDS scan -> write),
//    preserving ascending-j order (deterministic).
//  - P3: thread's k (= tid), hinge vs both anchors' positives.
//  - P4: fixed-tree f64 reduction -> per-block (sum, npos, ntrip).
// Final: one block, 256 threads, reduces 256 triples -> two scalars.
__global__ __launch_bounds__(512, 2) void triplet_main_k(
    const float* __restrict__ emb, const int* __restrict__ labels,
    double* __restrict__ partial)
{
    __shared__ float  drow[A][N];
    __shared__ float  posd[A][N];
    __shared__ int    cnt[A][8];
    __shared__ int    npos_s[A];
    __shared__ double red[24];   // [0..7]=sum, [8..15]=npos, [16..23]=ntrip

    const int i0   = blockIdx.x * A;
    const int tid  = threadIdx.x;
    const int lane = tid & 63;
    const int wid  = tid >> 6;
    const int sub  = tid & 7;

    // anchors -> registers (8-lane broadcast loads, L1/L2-hot)
    const float4* ea0 = reinterpret_cast<const float4*>(emb + (size_t)i0 * D);
    const float4* ea1 = reinterpret_cast<const float4*>(emb + (size_t)(i0 + 1) * D);
    const float4 a00 = ea0[sub], a01 = ea0[sub + 8], a02 = ea0[sub + 16], a03 = ea0[sub + 24];
    const float4 a10 = ea1[sub], a11 = ea1[sub + 8], a12 = ea1[sub + 16], a13 = ea1[sub + 24];

    const int lk  = labels[tid];        // this thread's k-label
    const int li0 = labels[i0];         // uniform broadcasts
    const int li1 = labels[i0 + 1];

    // ---- P1: coalesced distance rows for both anchors ----
    #pragma unroll
    for (int p = 0; p < 8; ++p) {
        const int r = p * 64 + (tid >> 3);
        const float4* er = reinterpret_cast<const float4*>(emb + (size_t)r * D);
        const float4 v0 = er[sub], v1 = er[sub + 8], v2 = er[sub + 16], v3 = er[sub + 24];
        float sq0 = 0.f, sq1 = 0.f;
        {
            float d0 = a00.x - v0.x, d1 = a00.y - v0.y, d2 = a00.z - v0.z, d3 = a00.w - v0.w;
            sq0 += d0 * d0 + d1 * d1 + d2 * d2 + d3 * d3;
            d0 = a01.x - v1.x; d1 = a01.y - v1.y; d2 = a01.z - v1.z; d3 = a01.w - v1.w;
            sq0 += d0 * d0 + d1 * d1 + d2 * d2 + d3 * d3;
            d0 = a02.x - v2.x; d1 = a02.y - v2.y; d2 = a02.z - v2.z; d3 = a02.w - v2.w;
            sq0 += d0 * d0 + d1 * d1 + d2 * d2 + d3 * d3;
            d0 = a03.x - v3.x; d1 = a03.y - v3.y; d2 = a03.z - v3.z; d3 = a03.w - v3.w;
            sq0 += d0 * d0 + d1 * d1 + d2 * d2 + d3 * d3;
        }
        {
            float d0 = a10.x - v0.x, d1 = a10.y - v0.y, d2 = a10.z - v0.z, d3 = a10.w - v0.w;
            sq1 += d0 * d0 + d1 * d1 + d2 * d2 + d3 * d3;
            d0 = a11.x - v1.x; d1 = a11.y - v1.y; d2 = a11.z - v1.z; d3 = a11.w - v1.w;
            sq1 += d0 * d0 + d1 * d1 + d2 * d2 + d3 * d3;
            d0 = a12.x - v2.x; d1 = a12.y - v2.y; d2 = a12.z - v2.z; d3 = a12.w - v2.w;
            sq1 += d0 * d0 + d1 * d1 + d2 * d2 + d3 * d3;
            d0 = a13.x - v3.x; d1 = a13.y - v3.y; d2 = a13.z - v3.z; d3 = a13.w - v3.w;
            sq1 += d0 * d0 + d1 * d1 + d2 * d2 + d3 * d3;
        }
        sq0 += __shfl_xor(sq0, 1); sq1 += __shfl_xor(sq1, 1);
        sq0 += __shfl_xor(sq0, 2); sq1 += __shfl_xor(sq1, 2);
        sq0 += __shfl_xor(sq0, 4); sq1 += __shfl_xor(sq1, 4);
        if (sub == 0) {
            drow[0][r] = (sq0 > 0.f) ? sqrtf(sq0) : 0.f;   // safe sqrt
            drow[1][r] = (sq1 > 0.f) ? sqrtf(sq1) : 0.f;
        }
    }
    __syncthreads();

    // ---- P2: parallel compaction, all 8 waves (ascending-j order kept) ----
    const int j = wid * 64 + lane;                 // each thread owns one j
    const bool p0 = (labels[j] == li0) && (j != i0);
    const bool p1 = (labels[j] == li1) && (j != i0 + 1);
    const unsigned long long m0 = __ballot(p0);
    const unsigned long long m1 = __ballot(p1);
    if (lane == 0) { cnt[0][wid] = __popcll(m0); cnt[1][wid] = __popcll(m1); }
    __syncthreads();
    int base0 = 0, base1 = 0;
    for (int w = 0; w < 8; ++w) {
        const int c0 = cnt[0][w], c1 = cnt[1][w];
        base0 += (w < wid) ? c0 : 0;
        base1 += (w < wid) ? c1 : 0;
    }
    if (p0) posd[0][base0 + __popcll(m0 & ((1ull << lane) - 1ull))] = drow[0][j];
    if (p1) posd[1][base1 + __popcll(m1 & ((1ull << lane) - 1ull))] = drow[1][j];
    if (tid == 0) {
        int t0 = 0, t1 = 0;
        #pragma unroll
        for (int w = 0; w < 8; ++w) { t0 += cnt[0][w]; t1 += cnt[1][w]; }
        npos_s[0] = t0; npos_s[1] = t1;
    }
    __syncthreads();

    // ---- P3: hinge accumulation, k = tid, both anchors ----
    double sum = 0.0;
    int np_i = 0, nt_i = 0;
    {
        const float dik = drow[0][tid];
        if (lk != li0) {
            const int npos = npos_s[0];
            #pragma unroll 4
            for (int p = 0; p < npos; ++p) {
                const float t = (posd[0][p] - dik) + MARGIN;  // reference op order
                if (t > EPS_T) { sum += (double)t; ++np_i; }
            }
            nt_i += npos;
        }
    }
    {
        const float dik = drow[1][tid];
        if (lk != li1) {
            const int npos = npos_s[1];
            #pragma unroll 4
            for (int p = 0; p < npos; ++p) {
                const float t = (posd[1][p] - dik) + MARGIN;
                if (t > EPS_T) { sum += (double)t; ++np_i; }
            }
            nt_i += npos;
        }
    }

    // ---- P4: fixed-tree reduction ----
    double s = sum, p = (double)np_i, t = (double)nt_i;
    #pragma unroll
    for (int off = 32; off > 0; off >>= 1) {
        s += __shfl_down(s, off);
        p += __shfl_down(p, off);
        t += __shfl_down(t, off);
    }
    if (lane == 0) { red[wid] = s; red[8 + wid] = p; red[16 + wid] = t; }
    __syncthreads();
    if (tid == 0) {
        double S = 0.0, P = 0.0, T = 0.0;
        #pragma unroll
        for (int w = 0; w < 8; ++w) { S += red[w]; P += red[8 + w]; T += red[16 + w]; }
        partial[blockIdx.x]            = S;
        partial[NBLK + blockIdx.x]     = P;
        partial[2 * NBLK + blockIdx.x] = T;
    }
}

__global__ __launch_bounds__(256) void triplet_final_k(
    const double* __restrict__ partial, float* __restrict__ out)
{
    __shared__ double red[12];
    const int tid  = threadIdx.x;
    const int lane = tid & 63;
    const int wid  = tid >> 6;
    double a = partial[tid];
    double b = partial[NBLK + tid];
    double c = partial[2 * NBLK + tid];
    #pragma unroll
    for (int off = 32; off > 0; off >>= 1) {
        a += __shfl_down(a, off);
        b += __shfl_down(b, off);
        c += __shfl_down(c, off);
    }
    if (lane == 0) { red[wid] = a; red[4 + wid] = b; red[8 + wid] = c; }
    __syncthreads();
    if (tid == 0) {
        const double S = red[0] + red[1] + red[2]  + red[3];
        const double P = red[4] + red[5] + red[6]  + red[7];
        const double T = red[8] + red[9] + red[10] + red[11];
        out[0] = (float)(S / (P + 1e-16));  // loss
        out[1] = (float)(P / (T + 1e-16));  // fraction_positive
    }
}

extern "C" void kernel_launch(void* const* d_in, const int* in_sizes, int n_in,
                              void* d_out, int out_size, void* d_ws, size_t ws_size,
                              hipStream_t stream) {
    const float* emb   = (const float*)d_in[0];   // [512,128] f32
    const int*   lab   = (const int*)d_in[1];     // [512] i32
    float*       out   = (float*)d_out;           // [2] f32: loss, fraction_positive
    double*      parts = (double*)d_ws;           // 3*NBLK doubles = 6 KB

    triplet_main_k<<<NBLK, 512, 0, stream>>>(emb, lab, parts);
    triplet_final_k<<<1, 256, 0, stream>>>(parts, out);
}